// Round 4
// baseline (184.612 us; speedup 1.0000x reference)
//
#include <hip/hip_runtime.h>

// PositionAttentionModule: B=2,C=64,C8=8,H=W=96,N=9216
// Round 4: 32x32x16 MFMA for QK and PV, TQ=128 (wave=32 rows), MCHUNK=96,
// PSTR=104 (odd 16B-group stride: conflict-free b128 frags), DPP-packed
// b32 P-stores. 576 blocks, all co-resident at 3 blocks/CU (41.4 KB LDS).

#define BN 2
#define CC 64
#define C8K 8
#define NN 9216
#define SPLIT 4
#define MCHUNK 96
#define MRANGE (NN / SPLIT)   // 2304 = 24 chunks of 96
#define TQ 128                // query rows per block (4 waves x 32)
#define NBLKQ (NN / TQ)       // 72
#define PREP_PX 64            // pixels per prep block
#define SHIFT 12.0f
#define PSTR 104              // shorts; 208 B row = 13 x 16B groups (odd mod 8)

typedef __attribute__((ext_vector_type(8))) short short8;
typedef __attribute__((ext_vector_type(16))) float f32x16;

// float offsets into workspace (~22.1 MB)
#define OFF_QB 0                                   // bf16 [b][n][8]
#define OFF_KT (OFF_QB + BN * NN * C8K / 2)        // bf16 [b][m][8]
#define OFF_VT (OFF_KT + BN * NN * C8K / 2)        // bf16 [b][c][m]
#define OFF_PACC (OFF_VT + BN * NN * CC / 2)
#define OFF_PSUM (OFF_PACC + SPLIT * BN * NN * CC)
#define WS_FLOATS (OFF_PSUM + SPLIT * BN * NN)

static __device__ inline unsigned f2bf(float x) {
    unsigned u = __builtin_bit_cast(unsigned, x);
    return (u + 0x7fff + ((u >> 16) & 1)) >> 16;   // RNE
}

// grid 288 blocks: each block = 64 pixels, 4 waves split the channel work.
__global__ __launch_bounds__(256) void pam_prep(
    const float* __restrict__ fm, const float* __restrict__ depth,
    const float* __restrict__ wa, const float* __restrict__ ba,
    const float* __restrict__ wb, const float* __restrict__ bb,
    const float* __restrict__ wc, const float* __restrict__ bc,
    const float* __restrict__ wd, const float* __restrict__ bd,
    unsigned short* __restrict__ Qb, unsigned short* __restrict__ Kt,
    unsigned short* __restrict__ Vt)
{
    __shared__ float s_wd[CC * CC];                // 16 KB
    __shared__ float s_wb[C8K * CC], s_wc[C8K * CC];
    __shared__ float s_wa[CC], s_ba[CC], s_bd[CC];
    __shared__ float s_bb[C8K], s_bc[C8K];
    __shared__ float qp[4][PREP_PX][C8K + 1];      // 9.2 KB

    int t = threadIdx.x;
    for (int i = t; i < CC * CC; i += 256) s_wd[i] = wd[i];
    for (int i = t; i < C8K * CC; i += 256) { s_wb[i] = wb[i]; s_wc[i] = wc[i]; }
    if (t < CC) { s_wa[t] = wa[t]; s_ba[t] = ba[t]; s_bd[t] = bd[t]; }
    if (t < C8K) { s_bb[t] = bb[t]; s_bc[t] = bc[t]; }
    __syncthreads();

    int px0 = blockIdx.x * PREP_PX;  // flat b*NN + m base
    int b = px0 / NN;
    int m0 = px0 - b * NN;
    int px = t & 63, w = t >> 6;
    int m = m0 + px;
    int gidx = px0 + px;

    float d = depth[gidx];
    float df[CC];
#pragma unroll
    for (int i = 0; i < CC; ++i) df[i] = fmaxf(s_wa[i] * d + s_ba[i], 0.0f);

    // V: wave w -> channels [w*16, w*16+16), coalesced bf16 stores
#pragma unroll 4
    for (int cc = 0; cc < 16; ++cc) {
        int c = w * 16 + cc;
        float acc = s_bd[c];
#pragma unroll
        for (int i = 0; i < CC; i += 4) {
            float4 wv = *(const float4*)&s_wd[c * CC + i];
            acc += wv.x * df[i] + wv.y * df[i + 1] + wv.z * df[i + 2] + wv.w * df[i + 3];
        }
        Vt[(b * CC + c) * NN + m] = (unsigned short)f2bf(acc);
    }

    // K: wave w -> k channels {2w, 2w+1}; pack pair into one dword store
    {
        float k0 = s_bc[2 * w], k1 = s_bc[2 * w + 1];
#pragma unroll
        for (int i = 0; i < CC; ++i) {
            k0 += s_wc[(2 * w) * CC + i] * df[i];
            k1 += s_wc[(2 * w + 1) * CC + i] * df[i];
        }
        unsigned pk = f2bf(k0) | (f2bf(k1) << 16);
        *(unsigned*)&Kt[(b * NN + m) * C8K + 2 * w] = pk;
    }

    // Q partials: wave w sums i in [w*16, w*16+16)
    {
        float q[C8K];
#pragma unroll
        for (int k = 0; k < C8K; ++k) q[k] = (w == 0) ? s_bb[k] : 0.0f;
#pragma unroll
        for (int ii = 0; ii < 16; ++ii) {
            int i = w * 16 + ii;
            float f = fm[(b * CC + i) * NN + m];
#pragma unroll
            for (int k = 0; k < C8K; ++k) q[k] += s_wb[k * CC + i] * f;
        }
#pragma unroll
        for (int k = 0; k < C8K; ++k) qp[w][px][k] = q[k];
    }
    __syncthreads();
    {
        int px2 = t >> 2, k2 = (t & 3) * 2;
        float a0 = qp[0][px2][k2] + qp[1][px2][k2] + qp[2][px2][k2] + qp[3][px2][k2];
        float a1 = qp[0][px2][k2 + 1] + qp[1][px2][k2 + 1] + qp[2][px2][k2 + 1] + qp[3][px2][k2 + 1];
        unsigned pk = f2bf(a0) | (f2bf(a1) << 16);
        *(unsigned*)&Qb[(px0 + px2) * C8K + k2] = pk;
    }
}

// grid (72, SPLIT, B), block 256 = 4 waves. Wave w owns query rows
// [w*32, w*32+32) x all 64 channels via two 32x32 accumulator tiles.
__global__ __launch_bounds__(256, 3) void pam_attn(
    const unsigned short* __restrict__ Qb, const unsigned short* __restrict__ Kt,
    const unsigned short* __restrict__ Vt,
    float* __restrict__ PACC, float* __restrict__ PSUM)
{
    __shared__ unsigned short p_s[TQ * PSTR];      // 26.0 KB bf16 [r][m]
    __shared__ unsigned short v_s[CC * PSTR];      // 13.0 KB bf16 [c][m]
    __shared__ unsigned short k_s[MCHUNK * C8K];   // 1.5 KB bf16 [m][k]

    int t = threadIdx.x;
    int n0 = blockIdx.x * TQ;
    int split = blockIdx.y;
    int b = blockIdx.z;
    int m_start = split * MRANGE;

    int lane = t & 63, w = t >> 6;
    int l31 = lane & 31, half = lane >> 5;

    // loop-invariant A-frag for QK: A[q=l31][k=half*8+j]; k>=8 is zero.
    short8 aq = {};
    if (lane < 32)
        aq = *(const short8*)&Qb[(b * NN + n0 + w * 32 + l31) * C8K];

    f32x16 acc0 = {}, acc1 = {};
    float rsum[16] = {};

    for (int ch = 0; ch < MRANGE; ch += MCHUNK) {
        int m0 = m_start + ch;
        __syncthreads();   // prior chunk's v_s/k_s reads complete
        // ---- stage V chunk: 64 rows x 96 shorts (3 b128 per thread) ----
        {
            int row = t >> 2, seg = t & 3;
            const unsigned short* gsrc = &Vt[(b * CC + row) * NN + m0 + seg * 8];
            unsigned short* ldst = &v_s[row * PSTR + seg * 8];
#pragma unroll
            for (int i = 0; i < 3; ++i)
                *(uint4*)(ldst + i * 32) = *(const uint4*)(gsrc + i * 32);
        }
        // ---- stage K chunk [96m][8k] ----
        if (t < MCHUNK)
            *(uint4*)&k_s[t * C8K] = *(const uint4*)&Kt[(b * NN + m0 + t) * C8K];
        __syncthreads();

        // ---- QK^T + exp + pack P, 3 m-tiles of 32 ----
#pragma unroll
        for (int mt = 0; mt < 3; ++mt) {
            short8 bk = *(const short8*)&k_s[(mt * 32 + l31) * C8K];
            f32x16 s = __builtin_amdgcn_mfma_f32_32x32x16_bf16(aq, bk, (f32x16){}, 0, 0, 0);
#pragma unroll
            for (int reg = 0; reg < 16; ++reg) {
                float e = __expf(s[reg] - SHIFT);
                rsum[reg] += e;
                unsigned hb = f2bf(e);
                unsigned other = __builtin_amdgcn_mov_dpp(hb, 0xB1, 0xF, 0xF, true); // xor-1
                if (!(lane & 1)) {
                    int prow = w * 32 + (reg & 3) + 8 * (reg >> 2) + 4 * half;
                    *(unsigned*)&p_s[prow * PSTR + mt * 32 + l31] = hb | (other << 16);
                }
            }
        }
        // ---- PV: 6 k-steps, 2 channel tiles (wave-private P rows) ----
#pragma unroll
        for (int ks = 0; ks < 6; ++ks) {
            const int off = ks * 16 + half * 8;
            short8 a  = *(const short8*)&p_s[(w * 32 + l31) * PSTR + off];
            short8 b0 = *(const short8*)&v_s[l31 * PSTR + off];
            short8 b1 = *(const short8*)&v_s[(32 + l31) * PSTR + off];
            acc0 = __builtin_amdgcn_mfma_f32_32x32x16_bf16(a, b0, acc0, 0, 0, 0);
            acc1 = __builtin_amdgcn_mfma_f32_32x32x16_bf16(a, b1, acc1, 0, 0, 0);
        }
    }

    // ---- epilogue ----
    int slab = (split * BN + b) * NN;
    // row sums: row(reg,half) spread across 32 lanes of the half; reduce.
#pragma unroll
    for (int reg = 0; reg < 16; ++reg) {
        float v = rsum[reg];
        v += __shfl_xor(v, 1);  v += __shfl_xor(v, 2);
        v += __shfl_xor(v, 4);  v += __shfl_xor(v, 8);
        v += __shfl_xor(v, 16);
        if (l31 == reg)
            PSUM[slab + n0 + w * 32 + (reg & 3) + 8 * (reg >> 2) + 4 * half] = v;
    }
    // acc tiles: D[row=(reg&3)+8*(reg>>2)+4*half][col=l31 (+32 for tile 1)]
    {
        float* base = &PACC[(slab + n0 + w * 32) * CC];
#pragma unroll
        for (int reg = 0; reg < 16; ++reg) {
            int r = (reg & 3) + 8 * (reg >> 2) + 4 * half;
            base[r * CC + l31] = acc0[reg];
            base[r * CC + 32 + l31] = acc1[reg];
        }
    }
}

// combine splits, normalize, transpose [n][c] -> out[b][c][n]
__global__ __launch_bounds__(256) void pam_norm(
    const float* __restrict__ PACC, const float* __restrict__ PSUM,
    float* __restrict__ out)
{
    __shared__ float tile[64 * 68];
    __shared__ float sums[64];
    int t = threadIdx.x;
    int n0 = blockIdx.x * 64;
    int b = blockIdx.y;
    if (t < 64) {
        float s = 0.0f;
#pragma unroll
        for (int sp = 0; sp < SPLIT; ++sp) s += PSUM[(sp * BN + b) * NN + n0 + t];
        sums[t] = s;
    }
    __syncthreads();
    // accumulate splits as float4, normalize, write [r][c] tile
#pragma unroll
    for (int it = 0; it < 4; ++it) {
        int idx = it * 256 + t;
        int r = idx >> 4, c4 = (idx & 15) * 4;
        float4 a = {0.f, 0.f, 0.f, 0.f};
#pragma unroll
        for (int sp = 0; sp < SPLIT; ++sp) {
            float4 p = *(const float4*)&PACC[((sp * BN + b) * NN + n0 + r) * CC + c4];
            a.x += p.x; a.y += p.y; a.z += p.z; a.w += p.w;
        }
        float inv = 1.0f / sums[r];
        a.x *= inv; a.y *= inv; a.z *= inv; a.w *= inv;
        *(float4*)&tile[r * 68 + c4] = a;
    }
    __syncthreads();
    // transpose out: coalesced over n
#pragma unroll
    for (int it = 0; it < 16; ++it) {
        int i = it * 256 + t;
        int c = i >> 6, nn = i & 63;
        out[(b * CC + c) * NN + n0 + nn] = tile[nn * 68 + c];
    }
}

extern "C" void kernel_launch(void* const* d_in, const int* in_sizes, int n_in,
                              void* d_out, int out_size, void* d_ws, size_t ws_size,
                              hipStream_t stream) {
    const float* fm    = (const float*)d_in[0];
    const float* depth = (const float*)d_in[1];
    const float* wa    = (const float*)d_in[2];
    const float* ba    = (const float*)d_in[3];
    const float* wb    = (const float*)d_in[4];
    const float* bb    = (const float*)d_in[5];
    const float* wc    = (const float*)d_in[6];
    const float* bc    = (const float*)d_in[7];
    const float* wd    = (const float*)d_in[8];
    const float* bd    = (const float*)d_in[9];
    float* out = (float*)d_out;

    float* ws = (float*)d_ws;
    unsigned short* Qb = (unsigned short*)(ws + OFF_QB);
    unsigned short* Kt = (unsigned short*)(ws + OFF_KT);
    unsigned short* Vt = (unsigned short*)(ws + OFF_VT);
    float* PACC = ws + OFF_PACC;
    float* PSUM = ws + OFF_PSUM;

    pam_prep<<<dim3((BN * NN) / PREP_PX), 256, 0, stream>>>(
        fm, depth, wa, ba, wb, bb, wc, bc, wd, bd, Qb, Kt, Vt);
    pam_attn<<<dim3(NBLKQ, SPLIT, BN), 256, 0, stream>>>(Qb, Kt, Vt, PACC, PSUM);
    pam_norm<<<dim3(NN / 64, BN), 256, 0, stream>>>(PACC, PSUM, out);
}